// Round 1
// 1159.193 us; speedup vs baseline: 1.0155x; 1.0155x over previous
//
#include <hip/hip_runtime.h>

// RecyclingEmbedder: out[i][j][p] = b[p] + (bin(d_ij) fired ? W[p][bin] : 0)
// d_ij = |x_i - x_j|^2, bins = linspace(3.25,20.75,15)^2, strict >lower & <upper.
// Output = 16-row table lookup -> pure write-BW problem (1.208 GB fp32).
//
// R2 lesson: nontemporal stores ~1.0 TB/s; plain stores win.
// R3 theory: measured 1177us likely = harness re-poison fill (~770us) + kernel
// (~405us @ 3 TB/s). Kernel-side gap is latency/TLP, not LDS BW:
//   - grid 3072 (2 blocks per row i, j-split) + __launch_bounds__(256,8)
//     -> 8 blocks/CU resident = 32 waves/CU (was 24).
//   - per-j LDS offset pre-multiplied (ushort idx*32) -> streaming iter is
//     ds_read_u16 + ds_read_b128 + store, one add on the critical path.

#define NBINS 15
#define NPTS  1536
#define DPAIR 128
#define JSPLIT 2                        // blocks per output row
#define JCHUNK (NPTS / JSPLIT)          // 768 j's per block
#define CHUNK_F4 (JCHUNK * DPAIR / 4)   // 24576 float4 per block

typedef float f32x4 __attribute__((ext_vector_type(4)));

__global__ __launch_bounds__(256, 8) void recycling_embedder_kernel(
    const float* __restrict__ x,   // [NPTS,3]
    const float* __restrict__ W,   // [DPAIR,NBINS] row-major
    const float* __restrict__ b,   // [DPAIR]
    float* __restrict__ out) {     // [NPTS,NPTS,DPAIR]
    __shared__ float table[16 * DPAIR];       // 8 KB: row 0 = b, row k = b + W[:,k-1]
    __shared__ unsigned short offs[JCHUNK];   // 1.5 KB: f4-offset (idx*32) per j

    const int i    = blockIdx.x >> 1;   // output row
    const int half = blockIdx.x & 1;    // which j-half of the row
    const int t    = threadIdx.x;

    // squared bin edges: all edges are exact multiples of 0.25 -> exact fp32;
    // squaring rounds identically to numpy's **2 in float32.
    float bins[NBINS];
#pragma unroll
    for (int k = 0; k < NBINS; ++k) {
        float e = 3.25f + 1.25f * (float)k;
        bins[k] = e * e;
    }

    // Build the 16-row lookup table (row 0 = b only; row k = b + W[:,k-1]).
    for (int e = t; e < 16 * DPAIR; e += 256) {
        int row = e >> 7;            // 0..15
        int p   = e & (DPAIR - 1);
        float v = b[p];
        if (row > 0) v += W[p * NBINS + (row - 1)];
        table[e] = v;
    }

    // Precompute table offset for every j in this block's half-row.
    const float xi0 = x[i * 3 + 0];
    const float xi1 = x[i * 3 + 1];
    const float xi2 = x[i * 3 + 2];
    const int j0 = half * JCHUNK;
    for (int jj = t; jj < JCHUNK; jj += 256) {
        int j = j0 + jj;
        float d;
        {
            // Bit-exact vs numpy: individually-rounded squares, left-to-right
            // sum, no fma contraction.
#pragma clang fp contract(off)
            float dx = xi0 - x[j * 3 + 0];
            float dy = xi1 - x[j * 3 + 1];
            float dz = xi2 - x[j * 3 + 2];
            d = dx * dx + dy * dy + dz * dz;
        }
        int cnt = 0, eq = 0;
#pragma unroll
        for (int k = 0; k < NBINS; ++k) {
            cnt += (d > bins[k]) ? 1 : 0;
            eq  |= (d == bins[k]) ? 1 : 0;
        }
        // exact edge hit -> one-hot all zero -> row 0 (b only)
        int idx = eq ? 0 : cnt;
        offs[jj] = (unsigned short)(idx * (DPAIR / 4));
    }
    __syncthreads();

    // Streaming phase: 96 iterations/thread, fully coalesced 1 KiB/wave-store.
    const f32x4* table4 = (const f32x4*)table;
    f32x4* ochunk = (f32x4*)out
                  + (size_t)i * (NPTS * DPAIR / 4)
                  + (size_t)(j0 * (DPAIR / 4));
#pragma unroll 4
    for (int l = t; l < CHUNK_F4; l += 256) {
        int jj     = l >> 5;          // j within this half-row
        int within = l & 31;          // float4 within the 128-float feature row
        ochunk[l] = table4[offs[jj] + within];
    }
}

extern "C" void kernel_launch(void* const* d_in, const int* in_sizes, int n_in,
                              void* d_out, int out_size, void* d_ws, size_t ws_size,
                              hipStream_t stream) {
    const float* x = (const float*)d_in[0];
    const float* W = (const float*)d_in[1];
    const float* b = (const float*)d_in[2];
    float* out = (float*)d_out;

    // 2 blocks per output row i: 3072 blocks -> 12 blocks/CU demand,
    // 8 resident (32 waves/CU, the cap).
    dim3 grid(NPTS * JSPLIT), block(256);
    recycling_embedder_kernel<<<grid, block, 0, stream>>>(x, W, b, out);
}